// Round 11
// baseline (808.457 us; speedup 1.0000x reference)
//
#include <hip/hip_runtime.h>
#include <hip/hip_fp16.h>

#define N_NODES_C 100000
#define N_EDGES_C 3200000
#define IN_F_C 10
#define HID_C 64
#define N_CLS_C 10
#define NEG_SLOPE_C 0.01f

#define NBUCK 98        // ceil(100000/1024); bucket = dst >> 10
#define BCAP  36864     // mean 32768, sigma ~180 -> +22 sigma headroom
#define TILE  2048      // edges per block in k_bucket
#define NRANGE 4        // src ranges of 25000 nodes (3.2 MB hs slice per range)
#define NDW   13        // dsts per wave in persistent gather (8192*13 >= 100000)
#define PGB   2048      // persistent gather blocks

// ---------------- pass 1: bucket partition (proven) ----------------
__global__ __launch_bounds__(256) void k_bucket(const int* __restrict__ src,
                                                const int* __restrict__ dst,
                                                int* __restrict__ bcur,
                                                int* __restrict__ pairs, int E) {
    __shared__ int lcnt[NBUCK];
    __shared__ int gbase[NBUCK];
    const int t = threadIdx.x;
    for (int i = t; i < NBUCK; i += 256) lcnt[i] = 0;
    __syncthreads();
    const int base = blockIdx.x * TILE;
    int p[8], r[8], nb[8];
#pragma unroll
    for (int i = 0; i < 8; ++i) {
        int e = base + t + i * 256;
        if (e < E) {
            int s = src[e], d = dst[e];
            int b = d >> 10;
            nb[i] = b;
            p[i] = (s << 10) | (d & 1023);
            r[i] = atomicAdd(&lcnt[b], 1);
        }
    }
    __syncthreads();
    for (int i = t; i < NBUCK; i += 256)
        gbase[i] = lcnt[i] ? atomicAdd(&bcur[i], lcnt[i]) : 0;
    __syncthreads();
#pragma unroll
    for (int i = 0; i < 8; ++i) {
        int e = base + t + i * 256;
        if (e < E) {
            int pos = gbase[nb[i]] + r[i];
            if (pos < BCAP) pairs[nb[i] * BCAP + pos] = p[i];
        }
    }
}

// ---------------- tiny scan of 98 bucket sizes ----------------
__global__ __launch_bounds__(128) void k_bscan(const int* __restrict__ bcur,
                                               int* __restrict__ bOff, int nbk) {
    __shared__ int s[128];
    int t = threadIdx.x;
    int v = (t < nbk) ? bcur[t] : 0;
    s[t] = v;
    __syncthreads();
    for (int off = 1; off < 128; off <<= 1) {
        int u = (t >= off) ? s[t - off] : 0;
        __syncthreads();
        s[t] += u;
        __syncthreads();
    }
    if (t < nbk) bOff[t] = s[t] - v;
}

// ---------------- pass 2: single-pass build, 4096-key (dst,range) hist + scan + placement ----------------
// rp2[(d<<2)+r] = start of (d, range r); rp2[4N] = E
__global__ __launch_bounds__(1024) void k_build(const int* __restrict__ pairs,
                                                const int* __restrict__ bcur,
                                                const int* __restrict__ bOff,
                                                int* __restrict__ rp2,
                                                float* __restrict__ dinv,
                                                int* __restrict__ col) {
    __shared__ int hist4[4096];          // key = (local_dst << 2) | range
    __shared__ int sm[1024];
    const int b = blockIdx.x;
    const int t = threadIdx.x;
    const int nE = min(bcur[b], BCAP);
    const int base = bOff[b];
    const int* pp = pairs + b * BCAP;

    for (int i = t; i < 4096; i += 1024) hist4[i] = 0;
    __syncthreads();
    for (int i = t; i < nE; i += 1024) {
        int p = pp[i];
        int s = p >> 10;
        atomicAdd(&hist4[((p & 1023) << 2) | (s / 25000)], 1);
    }
    __syncthreads();
    int c0 = hist4[4 * t], c1 = hist4[4 * t + 1], c2 = hist4[4 * t + 2], c3 = hist4[4 * t + 3];
    int c = c0 + c1 + c2 + c3;
    sm[t] = c;
    __syncthreads();
    for (int off = 1; off < 1024; off <<= 1) {
        int u = (t >= off) ? sm[t - off] : 0;
        __syncthreads();
        sm[t] += u;
        __syncthreads();
    }
    int rp = base + sm[t] - c;
    int o0 = rp, o1 = rp + c0, o2 = o1 + c1, o3 = o2 + c2;
    int gnode = (b << 10) + t;
    bool valid = gnode < N_NODES_C;
    if (valid) {
        *(int4*)(rp2 + (gnode << 2)) = make_int4(o0, o1, o2, o3);
        dinv[gnode] = rsqrtf((float)(c + 1));
        if (gnode == N_NODES_C - 1) rp2[4 * N_NODES_C] = rp + c;
    }
    __syncthreads();                      // rp2 written; safe to re-purpose hist4 as cursors
    hist4[4 * t] = o0; hist4[4 * t + 1] = o1; hist4[4 * t + 2] = o2; hist4[4 * t + 3] = o3;
    __syncthreads();
    for (int i = t; i < nE; i += 1024) {
        int p = pp[i];
        int s = p >> 10;
        int key = ((p & 1023) << 2) | (s / 25000);
        int idx = atomicAdd(&hist4[key], 1);
        col[idx] = s;
    }
}

// ---------------- layer-1 transform: hs = (x @ W1) * dinv ----------------
__global__ __launch_bounds__(256) void k_mm0(const float* __restrict__ x,
                                             const float* __restrict__ W,
                                             const float* __restrict__ dinv,
                                             __half* __restrict__ hs, int n) {
    __shared__ float4 W4[IN_F_C * 16];
    const int t = threadIdx.x;
    for (int i = t; i < IN_F_C * 16; i += 256) {
        int k = i >> 4, f4 = i & 15;
        W4[i] = ((const float4*)(W + k * HID_C))[f4];
    }
    __syncthreads();
    int idx = blockIdx.x * 256 + t;
    if (idx >= n * 16) return;
    int nn = idx >> 4, f4 = idx & 15;
    const float* row = x + nn * IN_F_C;
    float4 acc = make_float4(0.f, 0.f, 0.f, 0.f);
#pragma unroll
    for (int k = 0; k < IN_F_C; ++k) {
        float xv = row[k];
        float4 w = W4[k * 16 + f4];
        acc.x += xv * w.x; acc.y += xv * w.y; acc.z += xv * w.z; acc.w += xv * w.w;
    }
    float di = dinv[nn];
    ((__half2*)hs)[(nn << 5) + 2 * f4]     = __floats2half2_rn(acc.x * di, acc.y * di);
    ((__half2*)hs)[(nn << 5) + 2 * f4 + 1] = __floats2half2_rn(acc.z * di, acc.w * di);
}

// ---------------- persistent range-swept gather, register accumulators ----------------
__global__ __launch_bounds__(256) void k_pg(const int* __restrict__ rp2,
                                            const int* __restrict__ col,
                                            const __half2* __restrict__ hs,   // [n][32]
                                            const float* __restrict__ dinv,
                                            const float* __restrict__ bias,
                                            __half2* __restrict__ act,        // [n][32]
                                            int n) {
    const int t = threadIdx.x;
    const int lane = t & 63;
    const int wid  = t >> 6;
    const int half = lane >> 5;
    const int fl   = lane & 31;
    const int wave = (blockIdx.x << 2) + wid;
    const int base = wave * NDW;
    if (base >= n) return;

    float accx[NDW], accy[NDW];
#pragma unroll
    for (int j = 0; j < NDW; ++j) { accx[j] = 0.f; accy[j] = 0.f; }

    for (int r = 0; r < NRANGE; ++r) {
#pragma unroll
        for (int j = 0; j < NDW; ++j) {
            int d = base + j;
            if (d >= n) continue;
            int beg = rp2[(d << 2) + r];
            int end = (r < 3) ? rp2[(d << 2) + r + 1] : rp2[(d + 1) << 2];
            float ax = 0.f, ay = 0.f;
            int e = beg;
            for (; e + 7 < end; e += 8) {
                int i0 = e + half, i1 = e + 2 + half, i2 = e + 4 + half, i3 = e + 6 + half;
                int s0 = col[i0], s1 = col[i1], s2 = col[i2], s3 = col[i3];
                float2 v0 = __half22float2(hs[(s0 << 5) + fl]);
                float2 v1 = __half22float2(hs[(s1 << 5) + fl]);
                float2 v2 = __half22float2(hs[(s2 << 5) + fl]);
                float2 v3 = __half22float2(hs[(s3 << 5) + fl]);
                ax += (v0.x + v1.x) + (v2.x + v3.x);
                ay += (v0.y + v1.y) + (v2.y + v3.y);
            }
            if (e + 3 < end) {
                int i0 = e + half, i1 = e + 2 + half;
                int s0 = col[i0], s1 = col[i1];
                float2 v0 = __half22float2(hs[(s0 << 5) + fl]);
                float2 v1 = __half22float2(hs[(s1 << 5) + fl]);
                ax += v0.x + v1.x;
                ay += v0.y + v1.y;
                e += 4;
            }
            for (; e < end; e += 2) {
                int i = e + half;
                if (i < end) {
                    float2 v = __half22float2(hs[(col[i] << 5) + fl]);
                    ax += v.x; ay += v.y;
                }
            }
            accx[j] += ax; accy[j] += ay;
        }
    }

    // epilogue: combine halves, self-loop, scale, bias, leaky-relu
#pragma unroll
    for (int j = 0; j < NDW; ++j) {
        int d = base + j;
        if (d >= n) continue;
        float ax = accx[j] + __shfl_xor(accx[j], 32, 64);
        float ay = accy[j] + __shfl_xor(accy[j], 32, 64);
        if (!half) {
            float2 sv = __half22float2(hs[(d << 5) + fl]);
            float di = dinv[d];
            float2 bb = ((const float2*)bias)[fl];
            float vx = (ax + sv.x) * di + bb.x;
            float vy = (ay + sv.y) * di + bb.y;
            vx = vx > 0.f ? vx : NEG_SLOPE_C * vx;
            vy = vy > 0.f ? vy : NEG_SLOPE_C * vy;
            act[(d << 5) + fl] = __floats2half2_rn(vx, vy);
        }
    }
}

// ---------------- dense transform: hs[n,f'] = (act[n,:] @ W)[f'] * dinv[n], coalesced ----------------
__global__ __launch_bounds__(256) void k_xform(const __half* __restrict__ act,
                                               const float* __restrict__ W,   // [64][64]
                                               const float* __restrict__ dinv,
                                               __half* __restrict__ hs, int n) {
    __shared__ uint4 aLDS[64][8];
    __shared__ __half2 Wh2[32 * 64];
    const int t = threadIdx.x;
    const int base = blockIdx.x * 64;
    for (int i = t; i < 32 * 64; i += 256) {
        int k2 = i >> 6, f = i & 63;
        Wh2[i] = __floats2half2_rn(W[(2 * k2) * HID_C + f], W[(2 * k2 + 1) * HID_C + f]);
    }
    const uint4* aG = (const uint4*)act;
    for (int i = t; i < 64 * 8; i += 256) {
        int row = i >> 3, q = i & 7;
        int rr = min(base + row, n - 1);             // clamp (no OOB reads)
        aLDS[row][q] = aG[(size_t)rr * 8 + q];
    }
    __syncthreads();

    const int lane = t & 63;
    const int wid  = t >> 6;
#pragma unroll 4
    for (int ii = 0; ii < 16; ++ii) {
        int nn = wid * 16 + ii;
        int node = base + nn;
        const __half2* aRow = (const __half2*)&aLDS[nn][0];
        float s = 0.f;
#pragma unroll
        for (int k2 = 0; k2 < 32; ++k2) {
            float2 af = __half22float2(aRow[k2]);
            float2 wf = __half22float2(Wh2[(k2 << 6) + lane]);
            s += af.x * wf.x + af.y * wf.y;
        }
        if (node < n) hs[((size_t)node << 6) + lane] = __float2half(s * dinv[node]);
    }
}

// ---------------- final FC ----------------
__global__ __launch_bounds__(256) void k_fc(const __half* __restrict__ act,
                                            const float* __restrict__ W,   // [64][10]
                                            const float* __restrict__ b,
                                            float* __restrict__ out, int n) {
    __shared__ uint4 aLDS[64][8];
    __shared__ float2 Wf2[32 * N_CLS_C];
    __shared__ float bL[N_CLS_C];
    const int t = threadIdx.x;
    const int base = blockIdx.x * 64;
    for (int i = t; i < 32 * N_CLS_C; i += 256) {
        int k2 = i / N_CLS_C, c = i - k2 * N_CLS_C;
        Wf2[i] = make_float2(W[(2 * k2) * N_CLS_C + c], W[(2 * k2 + 1) * N_CLS_C + c]);
    }
    if (t < N_CLS_C) bL[t] = b[t];
    const uint4* aG = (const uint4*)act;
    for (int i = t; i < 64 * 8; i += 256) {
        int row = i >> 3, q = i & 7;
        int rr = min(base + row, n - 1);
        aLDS[row][q] = aG[(size_t)rr * 8 + q];
    }
    __syncthreads();

    const int lane = t & 63;
    const int wid  = t >> 6;
    if (lane >= N_CLS_C) return;
    for (int ii = 0; ii < 16; ++ii) {
        int nn = wid * 16 + ii;
        int node = base + nn;
        const __half2* aRow = (const __half2*)&aLDS[nn][0];
        float s = bL[lane];
#pragma unroll
        for (int k2 = 0; k2 < 32; ++k2) {
            float2 af = __half22float2(aRow[k2]);
            float2 wf = Wf2[k2 * N_CLS_C + lane];
            s += af.x * wf.x + af.y * wf.y;
        }
        if (node < n) out[(size_t)node * N_CLS_C + lane] = s;
    }
}

extern "C" void kernel_launch(void* const* d_in, const int* in_sizes, int n_in,
                              void* d_out, int out_size, void* d_ws, size_t ws_size,
                              hipStream_t stream) {
    const float* x   = (const float*)d_in[0];
    const int*   ei  = (const int*)d_in[1];
    const float* W1  = (const float*)d_in[2];
    const float* b1  = (const float*)d_in[3];
    const float* W2  = (const float*)d_in[4];
    const float* b2  = (const float*)d_in[5];
    const float* W3  = (const float*)d_in[6];
    const float* b3  = (const float*)d_in[7];
    const float* Wfc = (const float*)d_in[8];
    const float* bfc = (const float*)d_in[9];
    float* out = (float*)d_out;

    const int N = N_NODES_C;
    const int E = N_EDGES_C;
    const int* src = ei;
    const int* dst = ei + E;

    // workspace carve-up (16B aligned)
    float*  dinv = (float*)d_ws;                       // N
    int*    bcur = (int*)(dinv + N);                   // 128 (zeroed)
    int*    bOff = bcur + 128;                         // 128
    int*    rp2  = bOff + 128;                         // 4N+16
    int*    col  = rp2 + 4 * N + 16;                   // E
    int*    pairs = col + E;                           // NBUCK*BCAP ints
    __half* hsA  = (__half*)pairs;                     // N*64 halves (aliases pairs; dead after k_build)
    __half* hsB  = (__half*)(pairs + (size_t)NBUCK * BCAP);
    __half* act  = hsB + (size_t)N * HID_C;

    int gM0 = (N * 16 + 255) / 256;
    int gBK = (E + TILE - 1) / TILE;
    int gXF = (N + 63) / 64;

    // ---- CSR build (+ dinv), range-grouped rows, single placement pass ----
    hipMemsetAsync(bcur, 0, 128 * sizeof(int), stream);
    k_bucket<<<gBK, 256, 0, stream>>>(src, dst, bcur, pairs, E);
    k_bscan<<<1, 128, 0, stream>>>(bcur, bOff, NBUCK);
    k_build<<<NBUCK, 1024, 0, stream>>>(pairs, bcur, bOff, rp2, dinv, col);

    // ---- layer 1 ----
    k_mm0<<<gM0, 256, 0, stream>>>(x, W1, dinv, hsA, N);
    k_pg<<<PGB, 256, 0, stream>>>(rp2, col, (const __half2*)hsA, dinv, b1, (__half2*)act, N);
    // ---- layer 2 ----
    k_xform<<<gXF, 256, 0, stream>>>(act, W2, dinv, hsB, N);
    k_pg<<<PGB, 256, 0, stream>>>(rp2, col, (const __half2*)hsB, dinv, b2, (__half2*)act, N);
    // ---- layer 3 ----
    k_xform<<<gXF, 256, 0, stream>>>(act, W3, dinv, hsA, N);
    k_pg<<<PGB, 256, 0, stream>>>(rp2, col, (const __half2*)hsA, dinv, b3, (__half2*)act, N);
    // ---- final FC ----
    k_fc<<<gXF, 256, 0, stream>>>(act, Wfc, bfc, out, N);
}

// Round 12
// 511.742 us; speedup vs baseline: 1.5798x; 1.5798x over previous
//
#include <hip/hip_runtime.h>
#include <hip/hip_fp16.h>

#define N_NODES_C 100000
#define N_EDGES_C 3200000
#define IN_F_C 10
#define HID_C 64
#define N_CLS_C 10
#define NEG_SLOPE_C 0.01f

#define NBUCK 98        // ceil(100000/1024); bucket = dst >> 10
#define BCAP  36864     // mean 32768, sigma ~180 -> +22 sigma headroom
#define TILE  2048      // edges per block in k_bucket

// ---------------- pass 1: bucket partition (proven R5) ----------------
__global__ __launch_bounds__(256) void k_bucket(const int* __restrict__ src,
                                                const int* __restrict__ dst,
                                                int* __restrict__ bcur,
                                                int* __restrict__ pairs, int E) {
    __shared__ int lcnt[NBUCK];
    __shared__ int gbase[NBUCK];
    const int t = threadIdx.x;
    for (int i = t; i < NBUCK; i += 256) lcnt[i] = 0;
    __syncthreads();
    const int base = blockIdx.x * TILE;
    int p[8], r[8], nb[8];
#pragma unroll
    for (int i = 0; i < 8; ++i) {
        int e = base + t + i * 256;
        if (e < E) {
            int s = src[e], d = dst[e];
            int b = d >> 10;
            nb[i] = b;
            p[i] = (s << 10) | (d & 1023);
            r[i] = atomicAdd(&lcnt[b], 1);
        }
    }
    __syncthreads();
    for (int i = t; i < NBUCK; i += 256)
        gbase[i] = lcnt[i] ? atomicAdd(&bcur[i], lcnt[i]) : 0;
    __syncthreads();
#pragma unroll
    for (int i = 0; i < 8; ++i) {
        int e = base + t + i * 256;
        if (e < E) {
            int pos = gbase[nb[i]] + r[i];
            if (pos < BCAP) pairs[nb[i] * BCAP + pos] = p[i];
        }
    }
}

// ---------------- tiny scan of 98 bucket sizes ----------------
__global__ __launch_bounds__(128) void k_bscan(const int* __restrict__ bcur,
                                               int* __restrict__ bOff, int nbk) {
    __shared__ int s[128];
    int t = threadIdx.x;
    int v = (t < nbk) ? bcur[t] : 0;
    s[t] = v;
    __syncthreads();
    for (int off = 1; off < 128; off <<= 1) {
        int u = (t >= off) ? s[t - off] : 0;
        __syncthreads();
        s[t] += u;
        __syncthreads();
    }
    if (t < nbk) bOff[t] = s[t] - v;
}

// ---------------- pass 2: per-bucket hist + scan + row_ptr/dinv + placement (proven R8) ----------------
__global__ __launch_bounds__(1024) void k_build(const int* __restrict__ pairs,
                                                const int* __restrict__ bcur,
                                                const int* __restrict__ bOff,
                                                int* __restrict__ row_ptr,
                                                float* __restrict__ dinv,
                                                int* __restrict__ col) {
    __shared__ int hist[1024];
    __shared__ int sm[1024];
    const int b = blockIdx.x;
    const int t = threadIdx.x;
    const int n = min(bcur[b], BCAP);
    const int base = bOff[b];
    const int* pp = pairs + b * BCAP;

    hist[t] = 0;
    __syncthreads();
    for (int i = t; i < n; i += 1024) atomicAdd(&hist[pp[i] & 1023], 1);
    __syncthreads();
    int c = hist[t];
    sm[t] = c;
    __syncthreads();
    for (int off = 1; off < 1024; off <<= 1) {
        int u = (t >= off) ? sm[t - off] : 0;
        __syncthreads();
        sm[t] += u;
        __syncthreads();
    }
    int rp = base + sm[t] - c;
    int gnode = (b << 10) + t;
    if (gnode < N_NODES_C) {
        row_ptr[gnode] = rp;
        dinv[gnode] = rsqrtf((float)(c + 1));
        if (gnode == N_NODES_C - 1) row_ptr[N_NODES_C] = rp + c;
    }
    __syncthreads();
    sm[t] = rp;
    __syncthreads();
    for (int i = t; i < n; i += 1024) {
        int p = pp[i];
        int idx = atomicAdd(&sm[p & 1023], 1);
        col[idx] = p >> 10;
    }
}

// ---------------- layer-1 transform: hs = (x @ W1) * dinv (proven) ----------------
__global__ __launch_bounds__(256) void k_mm0(const float* __restrict__ x,
                                             const float* __restrict__ W,
                                             const float* __restrict__ dinv,
                                             __half* __restrict__ hs, int n) {
    __shared__ float4 W4[IN_F_C * 16];
    const int t = threadIdx.x;
    for (int i = t; i < IN_F_C * 16; i += 256) {
        int k = i >> 4, f4 = i & 15;
        W4[i] = ((const float4*)(W + k * HID_C))[f4];
    }
    __syncthreads();
    int idx = blockIdx.x * 256 + t;
    if (idx >= n * 16) return;
    int nn = idx >> 4, f4 = idx & 15;
    const float* row = x + nn * IN_F_C;
    float4 acc = make_float4(0.f, 0.f, 0.f, 0.f);
#pragma unroll
    for (int k = 0; k < IN_F_C; ++k) {
        float xv = row[k];
        float4 w = W4[k * 16 + f4];
        acc.x += xv * w.x; acc.y += xv * w.y; acc.z += xv * w.z; acc.w += xv * w.w;
    }
    float di = dinv[nn];
    ((__half2*)hs)[(nn << 5) + 2 * f4]     = __floats2half2_rn(acc.x * di, acc.y * di);
    ((__half2*)hs)[(nn << 5) + 2 * f4 + 1] = __floats2half2_rn(acc.z * di, acc.w * di);
}

// ---------------- lean gather (proven R5/R8: 92.6 us) ----------------
__global__ __launch_bounds__(256) void k_gather16(const int* __restrict__ row_ptr,
                                                  const int* __restrict__ col,
                                                  const __half2* __restrict__ hs,   // [n][32]
                                                  const float* __restrict__ dinv,
                                                  const float* __restrict__ b,
                                                  __half* __restrict__ act, int n) {
    const int lane = threadIdx.x & 63;
    const int half = lane >> 5;
    const int fl   = lane & 31;
    const int d = (blockIdx.x << 2) + (threadIdx.x >> 6);   // 4 waves / block
    if (d >= n) return;
    const int beg = row_ptr[d];
    const int end = row_ptr[d + 1];
    float2 acc = make_float2(0.f, 0.f);
    if (!half) {
        float2 v = __half22float2(hs[(d << 5) + fl]);
        acc.x = v.x; acc.y = v.y;
    }
    int e = beg;
    for (; e + 7 < end; e += 8) {
        int i0 = e + half, i1 = e + 2 + half, i2 = e + 4 + half, i3 = e + 6 + half;
        int s0 = col[i0], s1 = col[i1], s2 = col[i2], s3 = col[i3];
        float2 v0 = __half22float2(hs[(s0 << 5) + fl]);
        float2 v1 = __half22float2(hs[(s1 << 5) + fl]);
        float2 v2 = __half22float2(hs[(s2 << 5) + fl]);
        float2 v3 = __half22float2(hs[(s3 << 5) + fl]);
        acc.x += v0.x + v1.x + v2.x + v3.x;
        acc.y += v0.y + v1.y + v2.y + v3.y;
    }
    for (; e < end; e += 2) {
        int i = e + half;
        if (i < end) {
            float2 v = __half22float2(hs[(col[i] << 5) + fl]);
            acc.x += v.x; acc.y += v.y;
        }
    }
    acc.x += __shfl_xor(acc.x, 32, 64);
    acc.y += __shfl_xor(acc.y, 32, 64);
    if (!half) {
        float di = dinv[d];
        float2 bb = ((const float2*)b)[fl];
        float vx = acc.x * di + bb.x;
        float vy = acc.y * di + bb.y;
        vx = vx > 0.f ? vx : NEG_SLOPE_C * vx;
        vy = vy > 0.f ? vy : NEG_SLOPE_C * vy;
        ((__half2*)act)[(d << 5) + fl] = __floats2half2_rn(vx, vy);
    }
}

// ---------------- register-tiled dense transform: hs = (act @ W) * dinv ----------------
// 64 nodes/block; thread (f4,j4) owns 4 nodes x 4 features; per k: 2x ds_read_b128 -> 16 FMA
__global__ __launch_bounds__(256) void k_xform(const __half* __restrict__ act,
                                               const float* __restrict__ W,   // [64][64]
                                               const float* __restrict__ dinv,
                                               __half* __restrict__ hs, int n) {
    __shared__ float Ast[HID_C][68];      // transposed act: Ast[k][node], stride 68 (16B-aligned)
    __shared__ float4 Wq[HID_C * 16];     // W quads: Wq[k*16+f4] = W[k][4f4..4f4+3]
    const int t = threadIdx.x;
    const int base = blockIdx.x * 64;

    for (int i = t; i < HID_C * 16; i += 256) Wq[i] = ((const float4*)W)[i];

    {   // coalesced stage + transpose: lane r = t&63 spans 64 rows -> <=2-way bank conflicts
        const int r = t & 63, qg = t >> 6;
        const uint4* aG = (const uint4*)act;          // 8 uint4 per 64-half row
        int node = min(base + r, n - 1);              // clamp, no OOB
#pragma unroll
        for (int qi = 0; qi < 2; ++qi) {
            int q = qg + qi * 4;                      // 0..7
            uint4 raw = aG[(size_t)node * 8 + q];
            const __half2* hp = (const __half2*)&raw; // 4 half2 = 8 halves
#pragma unroll
            for (int j = 0; j < 4; ++j) {
                float2 f = __half22float2(hp[j]);
                Ast[q * 8 + 2 * j][r]     = f.x;
                Ast[q * 8 + 2 * j + 1][r] = f.y;
            }
        }
    }
    __syncthreads();

    const int f4 = t & 15, j4 = t >> 4;               // j4 0..15 -> node group 4*j4
    float4 s0 = make_float4(0.f,0.f,0.f,0.f), s1 = s0, s2 = s0, s3 = s0;
#pragma unroll
    for (int k = 0; k < HID_C; ++k) {
        float4 w = Wq[k * 16 + f4];
        float4 a = *(const float4*)&Ast[k][4 * j4];
        s0.x += a.x*w.x; s0.y += a.x*w.y; s0.z += a.x*w.z; s0.w += a.x*w.w;
        s1.x += a.y*w.x; s1.y += a.y*w.y; s1.z += a.y*w.z; s1.w += a.y*w.w;
        s2.x += a.z*w.x; s2.y += a.z*w.y; s2.z += a.z*w.z; s2.w += a.z*w.w;
        s3.x += a.w*w.x; s3.y += a.w*w.y; s3.z += a.w*w.z; s3.w += a.w*w.w;
    }
    float4 sv[4] = {s0, s1, s2, s3};
#pragma unroll
    for (int jj = 0; jj < 4; ++jj) {
        int node = base + 4 * j4 + jj;
        if (node < n) {
            float di = dinv[node];
            ((__half2*)hs)[(node << 5) + 2 * f4]     = __floats2half2_rn(sv[jj].x * di, sv[jj].y * di);
            ((__half2*)hs)[(node << 5) + 2 * f4 + 1] = __floats2half2_rn(sv[jj].z * di, sv[jj].w * di);
        }
    }
}

// ---------------- final FC: out = act @ Wfc + bfc (coalesced staging) ----------------
__global__ __launch_bounds__(256) void k_fc(const __half* __restrict__ act,
                                            const float* __restrict__ W,   // [64][10]
                                            const float* __restrict__ b,
                                            float* __restrict__ out, int n) {
    __shared__ uint4 aLDS[64][8];
    __shared__ float2 Wf2[32 * N_CLS_C];
    __shared__ float bL[N_CLS_C];
    const int t = threadIdx.x;
    const int base = blockIdx.x * 64;
    for (int i = t; i < 32 * N_CLS_C; i += 256) {
        int k2 = i / N_CLS_C, c = i - k2 * N_CLS_C;
        Wf2[i] = make_float2(W[(2 * k2) * N_CLS_C + c], W[(2 * k2 + 1) * N_CLS_C + c]);
    }
    if (t < N_CLS_C) bL[t] = b[t];
    const uint4* aG = (const uint4*)act;
    for (int i = t; i < 64 * 8; i += 256) {
        int row = i >> 3, q = i & 7;
        int rr = min(base + row, n - 1);
        aLDS[row][q] = aG[(size_t)rr * 8 + q];
    }
    __syncthreads();

    const int lane = t & 63;
    const int wid  = t >> 6;
    if (lane >= N_CLS_C) return;
    for (int ii = 0; ii < 16; ++ii) {
        int nn = wid * 16 + ii;
        int node = base + nn;
        const __half2* aRow = (const __half2*)&aLDS[nn][0];
        float s = bL[lane];
#pragma unroll
        for (int k2 = 0; k2 < 32; ++k2) {
            float2 af = __half22float2(aRow[k2]);
            float2 wf = Wf2[k2 * N_CLS_C + lane];
            s += af.x * wf.x + af.y * wf.y;
        }
        if (node < n) out[(size_t)node * N_CLS_C + lane] = s;
    }
}

extern "C" void kernel_launch(void* const* d_in, const int* in_sizes, int n_in,
                              void* d_out, int out_size, void* d_ws, size_t ws_size,
                              hipStream_t stream) {
    const float* x   = (const float*)d_in[0];
    const int*   ei  = (const int*)d_in[1];
    const float* W1  = (const float*)d_in[2];
    const float* b1  = (const float*)d_in[3];
    const float* W2  = (const float*)d_in[4];
    const float* b2  = (const float*)d_in[5];
    const float* W3  = (const float*)d_in[6];
    const float* b3  = (const float*)d_in[7];
    const float* Wfc = (const float*)d_in[8];
    const float* bfc = (const float*)d_in[9];
    float* out = (float*)d_out;

    const int N = N_NODES_C;
    const int E = N_EDGES_C;
    const int* src = ei;
    const int* dst = ei + E;

    // workspace carve-up (16B aligned)
    float*  dinv    = (float*)d_ws;                   // N
    int*    bcur    = (int*)(dinv + N);               // 128 (zeroed)
    int*    bOff    = bcur + 128;                     // 128
    int*    row_ptr = bOff + 128;                     // N+4
    int*    col     = row_ptr + N + 4;                // E
    int*    pairs   = col + E;                        // NBUCK*BCAP ints
    __half* hsA     = (__half*)pairs;                 // N*64 halves (aliases pairs; dead after k_build)
    __half* hsB     = (__half*)(pairs + (size_t)NBUCK * BCAP);
    __half* act     = hsB + (size_t)N * HID_C;

    int gN4 = (N + 3) / 4;                            // 25000
    int gM0 = (N * 16 + 255) / 256;                   // 6250
    int gBK = (E + TILE - 1) / TILE;                  // 1563
    int gXF = (N + 63) / 64;                          // 1563

    // ---- CSR build (+ dinv) ----
    hipMemsetAsync(bcur, 0, 128 * sizeof(int), stream);
    k_bucket<<<gBK, 256, 0, stream>>>(src, dst, bcur, pairs, E);
    k_bscan<<<1, 128, 0, stream>>>(bcur, bOff, NBUCK);
    k_build<<<NBUCK, 1024, 0, stream>>>(pairs, bcur, bOff, row_ptr, dinv, col);

    // ---- layer 1 ----
    k_mm0<<<gM0, 256, 0, stream>>>(x, W1, dinv, hsA, N);
    k_gather16<<<gN4, 256, 0, stream>>>(row_ptr, col, (const __half2*)hsA, dinv, b1, act, N);
    // ---- layer 2 ----
    k_xform<<<gXF, 256, 0, stream>>>(act, W2, dinv, hsB, N);
    k_gather16<<<gN4, 256, 0, stream>>>(row_ptr, col, (const __half2*)hsB, dinv, b2, act, N);
    // ---- layer 3 ----
    k_xform<<<gXF, 256, 0, stream>>>(act, W3, dinv, hsA, N);
    k_gather16<<<gN4, 256, 0, stream>>>(row_ptr, col, (const __half2*)hsA, dinv, b3, act, N);
    // ---- final FC ----
    k_fc<<<gXF, 256, 0, stream>>>(act, Wfc, bfc, out, N);
}

// Round 13
// 440.593 us; speedup vs baseline: 1.8349x; 1.1615x over previous
//
#include <hip/hip_runtime.h>
#include <hip/hip_fp16.h>

#define N_NODES_C 100000
#define N_EDGES_C 3200000
#define IN_F_C 10
#define HID_C 64
#define N_CLS_C 10
#define NEG_SLOPE_C 0.01f

#define NBUCK 98        // ceil(100000/1024); bucket = dst >> 10
#define BCAP  36864     // mean 32768, sigma ~180 -> +22 sigma headroom
#define TILE  2048      // edges per block in k_bucket

typedef _Float16 f16x2 __attribute__((ext_vector_type(2)));

__device__ __forceinline__ float fdot2(unsigned int a, unsigned int b, float c) {
#if defined(__has_builtin) && __has_builtin(__builtin_amdgcn_fdot2)
    return __builtin_amdgcn_fdot2(__builtin_bit_cast(f16x2, a), __builtin_bit_cast(f16x2, b), c, false);
#else
    __half2 ah = __builtin_bit_cast(__half2, a), bh = __builtin_bit_cast(__half2, b);
    float2 af = __half22float2(ah), bf = __half22float2(bh);
    return c + af.x * bf.x + af.y * bf.y;
#endif
}

// ---------------- pass 1: bucket partition (proven) ----------------
__global__ __launch_bounds__(256) void k_bucket(const int* __restrict__ src,
                                                const int* __restrict__ dst,
                                                int* __restrict__ bcur,
                                                int* __restrict__ pairs, int E) {
    __shared__ int lcnt[NBUCK];
    __shared__ int gbase[NBUCK];
    const int t = threadIdx.x;
    for (int i = t; i < NBUCK; i += 256) lcnt[i] = 0;
    __syncthreads();
    const int base = blockIdx.x * TILE;
    int p[8], r[8], nb[8];
#pragma unroll
    for (int i = 0; i < 8; ++i) {
        int e = base + t + i * 256;
        if (e < E) {
            int s = src[e], d = dst[e];
            int b = d >> 10;
            nb[i] = b;
            p[i] = (s << 10) | (d & 1023);
            r[i] = atomicAdd(&lcnt[b], 1);
        }
    }
    __syncthreads();
    for (int i = t; i < NBUCK; i += 256)
        gbase[i] = lcnt[i] ? atomicAdd(&bcur[i], lcnt[i]) : 0;
    __syncthreads();
#pragma unroll
    for (int i = 0; i < 8; ++i) {
        int e = base + t + i * 256;
        if (e < E) {
            int pos = gbase[nb[i]] + r[i];
            if (pos < BCAP) pairs[nb[i] * BCAP + pos] = p[i];
        }
    }
}

// ---------------- tiny scan of 98 bucket sizes ----------------
__global__ __launch_bounds__(128) void k_bscan(const int* __restrict__ bcur,
                                               int* __restrict__ bOff, int nbk) {
    __shared__ int s[128];
    int t = threadIdx.x;
    int v = (t < nbk) ? bcur[t] : 0;
    s[t] = v;
    __syncthreads();
    for (int off = 1; off < 128; off <<= 1) {
        int u = (t >= off) ? s[t - off] : 0;
        __syncthreads();
        s[t] += u;
        __syncthreads();
    }
    if (t < nbk) bOff[t] = s[t] - v;
}

// ---------------- pass 2: per-bucket hist + scan + row_ptr/dinv + placement (proven) ----------------
__global__ __launch_bounds__(1024) void k_build(const int* __restrict__ pairs,
                                                const int* __restrict__ bcur,
                                                const int* __restrict__ bOff,
                                                int* __restrict__ row_ptr,
                                                float* __restrict__ dinv,
                                                int* __restrict__ col) {
    __shared__ int hist[1024];
    __shared__ int sm[1024];
    const int b = blockIdx.x;
    const int t = threadIdx.x;
    const int n = min(bcur[b], BCAP);
    const int base = bOff[b];
    const int* pp = pairs + b * BCAP;

    hist[t] = 0;
    __syncthreads();
    for (int i = t; i < n; i += 1024) atomicAdd(&hist[pp[i] & 1023], 1);
    __syncthreads();
    int c = hist[t];
    sm[t] = c;
    __syncthreads();
    for (int off = 1; off < 1024; off <<= 1) {
        int u = (t >= off) ? sm[t - off] : 0;
        __syncthreads();
        sm[t] += u;
        __syncthreads();
    }
    int rp = base + sm[t] - c;
    int gnode = (b << 10) + t;
    if (gnode < N_NODES_C) {
        row_ptr[gnode] = rp;
        dinv[gnode] = rsqrtf((float)(c + 1));
        if (gnode == N_NODES_C - 1) row_ptr[N_NODES_C] = rp + c;
    }
    __syncthreads();
    sm[t] = rp;
    __syncthreads();
    for (int i = t; i < n; i += 1024) {
        int p = pp[i];
        int idx = atomicAdd(&sm[p & 1023], 1);
        col[idx] = p >> 10;
    }
}

// ---------------- layer-1 transform: hs = (x @ W1) * dinv (proven) ----------------
__global__ __launch_bounds__(256) void k_mm0(const float* __restrict__ x,
                                             const float* __restrict__ W,
                                             const float* __restrict__ dinv,
                                             __half* __restrict__ hs, int n) {
    __shared__ float4 W4[IN_F_C * 16];
    const int t = threadIdx.x;
    for (int i = t; i < IN_F_C * 16; i += 256) {
        int k = i >> 4, f4 = i & 15;
        W4[i] = ((const float4*)(W + k * HID_C))[f4];
    }
    __syncthreads();
    int idx = blockIdx.x * 256 + t;
    if (idx >= n * 16) return;
    int nn = idx >> 4, f4 = idx & 15;
    const float* row = x + nn * IN_F_C;
    float4 acc = make_float4(0.f, 0.f, 0.f, 0.f);
#pragma unroll
    for (int k = 0; k < IN_F_C; ++k) {
        float xv = row[k];
        float4 w = W4[k * 16 + f4];
        acc.x += xv * w.x; acc.y += xv * w.y; acc.z += xv * w.z; acc.w += xv * w.w;
    }
    float di = dinv[nn];
    ((__half2*)hs)[(nn << 5) + 2 * f4]     = __floats2half2_rn(acc.x * di, acc.y * di);
    ((__half2*)hs)[(nn << 5) + 2 * f4 + 1] = __floats2half2_rn(acc.z * di, acc.w * di);
}

// ---------------- weight pre-pack: W[64][64] fp32 -> Wh[k8*64+f] = 8 halves of W[8k8..][f] ----------------
__global__ __launch_bounds__(256) void k_wcvt(const float* __restrict__ W, uint4* __restrict__ wh) {
    int i = blockIdx.x * 256 + threadIdx.x;      // 512 entries
    if (i >= 8 * HID_C) return;
    int k8 = i >> 6, f = i & 63;
    __half2 h[4];
#pragma unroll
    for (int j = 0; j < 4; ++j)
        h[j] = __floats2half2_rn(W[(8 * k8 + 2 * j) * HID_C + f],
                                 W[(8 * k8 + 2 * j + 1) * HID_C + f]);
    wh[i] = *(uint4*)h;
}

// ---------------- fused: lean gather + epilogue + fdot2 transform ----------------
// hs_next[d][f'] = ( lrelu((hs[d]+sum_e hs[col[e]])*dinv[d] + b) @ Wn )[f'] * dinv[d]
__global__ __launch_bounds__(256) void k_gftL(const int* __restrict__ row_ptr,
                                              const int* __restrict__ col,
                                              const __half2* __restrict__ hs,   // [n][32]
                                              const float* __restrict__ dinv,
                                              const float* __restrict__ bias,
                                              const uint4* __restrict__ wh,     // pre-packed fp16 W
                                              __half* __restrict__ hnext, int n) {
    __shared__ uint4 WhL[8 * HID_C];             // 8 KB
    __shared__ __half2 rowh[4][32];              // act row fp16 per wave
    const int t = threadIdx.x;
#pragma unroll
    for (int i = 0; i < 2; ++i) WhL[t + i * 256] = wh[t + i * 256];
    __syncthreads();

    const int lane = t & 63;
    const int wid  = t >> 6;
    const int half = lane >> 5;
    const int fl   = lane & 31;
    const int d = (blockIdx.x << 2) + wid;
    if (d >= n) return;
    const int beg = row_ptr[d];
    const int end = row_ptr[d + 1];

    float2 acc = make_float2(0.f, 0.f);
    if (!half) {                                 // self loop on half 0
        float2 v = __half22float2(hs[(d << 5) + fl]);
        acc.x = v.x; acc.y = v.y;
    }
    int e = beg;
    for (; e + 7 < end; e += 8) {                // proven lean loop: 4 loads in flight/lane
        int i0 = e + half, i1 = e + 2 + half, i2 = e + 4 + half, i3 = e + 6 + half;
        int s0 = col[i0], s1 = col[i1], s2 = col[i2], s3 = col[i3];
        float2 v0 = __half22float2(hs[(s0 << 5) + fl]);
        float2 v1 = __half22float2(hs[(s1 << 5) + fl]);
        float2 v2 = __half22float2(hs[(s2 << 5) + fl]);
        float2 v3 = __half22float2(hs[(s3 << 5) + fl]);
        acc.x += v0.x + v1.x + v2.x + v3.x;
        acc.y += v0.y + v1.y + v2.y + v3.y;
    }
    for (; e < end; e += 2) {
        int i = e + half;
        if (i < end) {
            float2 v = __half22float2(hs[(col[i] << 5) + fl]);
            acc.x += v.x; acc.y += v.y;
        }
    }
    acc.x += __shfl_xor(acc.x, 32, 64);
    acc.y += __shfl_xor(acc.y, 32, 64);

    const float di = dinv[d];
    if (!half) {                                 // epilogue -> fp16 act row in LDS
        float2 bb = ((const float2*)bias)[fl];
        float vx = acc.x * di + bb.x;
        float vy = acc.y * di + bb.y;
        vx = vx > 0.f ? vx : NEG_SLOPE_C * vx;
        vy = vy > 0.f ? vy : NEG_SLOPE_C * vy;
        rowh[wid][fl] = __floats2half2_rn(vx, vy);
    }
    // wave-synchronous LDS read-back; fdot2 transform (fp32 accumulate)
    {
        float s = 0.f;
        const uint4* rq = (const uint4*)rowh[wid];
#pragma unroll
        for (int k8 = 0; k8 < 8; ++k8) {
            uint4 wv = WhL[(k8 << 6) + lane];
            uint4 rv = rq[k8];                   // broadcast
            s = fdot2(rv.x, wv.x, s);
            s = fdot2(rv.y, wv.y, s);
            s = fdot2(rv.z, wv.z, s);
            s = fdot2(rv.w, wv.w, s);
        }
        hnext[(d << 6) + lane] = __float2half(s * di);
    }
}

// ---------------- fused: lean gather + epilogue + final FC (fp32 W) ----------------
__global__ __launch_bounds__(256) void k_gfcL(const int* __restrict__ row_ptr,
                                              const int* __restrict__ col,
                                              const __half2* __restrict__ hs,
                                              const float* __restrict__ dinv,
                                              const float* __restrict__ bias,
                                              const float* __restrict__ Wn,   // [64][10]
                                              const float* __restrict__ bn,
                                              float* __restrict__ out, int n) {
    __shared__ float4 Ws4[16 * N_CLS_C];
    __shared__ float rowbuf[4][64];
    const int t = threadIdx.x;
    for (int i = t; i < 16 * N_CLS_C; i += 256) {
        int k4 = i / N_CLS_C, f = i - k4 * N_CLS_C;
        Ws4[i] = make_float4(Wn[(4 * k4 + 0) * N_CLS_C + f], Wn[(4 * k4 + 1) * N_CLS_C + f],
                             Wn[(4 * k4 + 2) * N_CLS_C + f], Wn[(4 * k4 + 3) * N_CLS_C + f]);
    }
    __syncthreads();

    const int lane = t & 63;
    const int wid  = t >> 6;
    const int half = lane >> 5;
    const int fl   = lane & 31;
    const int d = (blockIdx.x << 2) + wid;
    if (d >= n) return;
    const int beg = row_ptr[d];
    const int end = row_ptr[d + 1];

    float2 acc = make_float2(0.f, 0.f);
    if (!half) {
        float2 v = __half22float2(hs[(d << 5) + fl]);
        acc.x = v.x; acc.y = v.y;
    }
    int e = beg;
    for (; e + 7 < end; e += 8) {
        int i0 = e + half, i1 = e + 2 + half, i2 = e + 4 + half, i3 = e + 6 + half;
        int s0 = col[i0], s1 = col[i1], s2 = col[i2], s3 = col[i3];
        float2 v0 = __half22float2(hs[(s0 << 5) + fl]);
        float2 v1 = __half22float2(hs[(s1 << 5) + fl]);
        float2 v2 = __half22float2(hs[(s2 << 5) + fl]);
        float2 v3 = __half22float2(hs[(s3 << 5) + fl]);
        acc.x += v0.x + v1.x + v2.x + v3.x;
        acc.y += v0.y + v1.y + v2.y + v3.y;
    }
    for (; e < end; e += 2) {
        int i = e + half;
        if (i < end) {
            float2 v = __half22float2(hs[(col[i] << 5) + fl]);
            acc.x += v.x; acc.y += v.y;
        }
    }
    acc.x += __shfl_xor(acc.x, 32, 64);
    acc.y += __shfl_xor(acc.y, 32, 64);

    const float di = dinv[d];
    if (!half) {
        float2 bb = ((const float2*)bias)[fl];
        float vx = acc.x * di + bb.x;
        float vy = acc.y * di + bb.y;
        vx = vx > 0.f ? vx : NEG_SLOPE_C * vx;
        vy = vy > 0.f ? vy : NEG_SLOPE_C * vy;
        ((float2*)rowbuf[wid])[fl] = make_float2(vx, vy);
    }
    if (lane < N_CLS_C) {
        float s = bn[lane];
        const float4* rb = (const float4*)rowbuf[wid];
#pragma unroll
        for (int k4 = 0; k4 < 16; ++k4) {
            float4 r4 = rb[k4];
            float4 w4 = Ws4[k4 * N_CLS_C + lane];
            s += r4.x * w4.x + r4.y * w4.y + r4.z * w4.z + r4.w * w4.w;
        }
        out[d * N_CLS_C + lane] = s;
    }
}

extern "C" void kernel_launch(void* const* d_in, const int* in_sizes, int n_in,
                              void* d_out, int out_size, void* d_ws, size_t ws_size,
                              hipStream_t stream) {
    const float* x   = (const float*)d_in[0];
    const int*   ei  = (const int*)d_in[1];
    const float* W1  = (const float*)d_in[2];
    const float* b1  = (const float*)d_in[3];
    const float* W2  = (const float*)d_in[4];
    const float* b2  = (const float*)d_in[5];
    const float* W3  = (const float*)d_in[6];
    const float* b3  = (const float*)d_in[7];
    const float* Wfc = (const float*)d_in[8];
    const float* bfc = (const float*)d_in[9];
    float* out = (float*)d_out;

    const int N = N_NODES_C;
    const int E = N_EDGES_C;
    const int* src = ei;
    const int* dst = ei + E;

    // workspace carve-up (16B aligned)
    float*  dinv    = (float*)d_ws;                   // N
    int*    bcur    = (int*)(dinv + N);               // 128 (zeroed)
    int*    bOff    = bcur + 128;                     // 128
    int*    row_ptr = bOff + 128;                     // N+4
    uint4*  wh2     = (uint4*)(row_ptr + N + 4);      // 512
    uint4*  wh3     = wh2 + 512;                      // 512
    int*    col     = (int*)(wh3 + 512);              // E
    int*    pairs   = col + E;                        // NBUCK*BCAP ints
    __half* hsA     = (__half*)pairs;                 // N*64 halves (aliases pairs; dead after k_build)
    __half* hsB     = (__half*)(pairs + (size_t)NBUCK * BCAP);

    int gN4 = (N + 3) / 4;                            // 25000
    int gM0 = (N * 16 + 255) / 256;                   // 6250
    int gBK = (E + TILE - 1) / TILE;                  // 1563

    // ---- CSR build (+ dinv) ----
    hipMemsetAsync(bcur, 0, 128 * sizeof(int), stream);
    k_bucket<<<gBK, 256, 0, stream>>>(src, dst, bcur, pairs, E);
    k_bscan<<<1, 128, 0, stream>>>(bcur, bOff, NBUCK);
    k_build<<<NBUCK, 1024, 0, stream>>>(pairs, bcur, bOff, row_ptr, dinv, col);

    // ---- weight pre-pack (fp16, 8-per-k layout) ----
    k_wcvt<<<2, 256, 0, stream>>>(W2, wh2);
    k_wcvt<<<2, 256, 0, stream>>>(W3, wh3);

    // ---- layer 1 transform ----
    k_mm0<<<gM0, 256, 0, stream>>>(x, W1, dinv, hsA, N);

    // ---- fused lean-gather + transform chain ----
    k_gftL<<<gN4, 256, 0, stream>>>(row_ptr, col, (const __half2*)hsA, dinv, b1, wh2, hsB, N);
    k_gftL<<<gN4, 256, 0, stream>>>(row_ptr, col, (const __half2*)hsB, dinv, b2, wh3, hsA, N);
    k_gfcL<<<gN4, 256, 0, stream>>>(row_ptr, col, (const __half2*)hsA, dinv, b3, Wfc, bfc, out, N);
}

// Round 14
// 414.728 us; speedup vs baseline: 1.9494x; 1.0624x over previous
//
#include <hip/hip_runtime.h>
#include <hip/hip_fp16.h>

#define N_NODES_C 100000
#define N_EDGES_C 3200000
#define IN_F_C 10
#define HID_C 64
#define N_CLS_C 10
#define NEG_SLOPE_C 0.01f

#define NBUCK 98        // ceil(100000/1024); bucket = dst >> 10
#define BCAP  36864     // mean 32768, sigma ~180 -> +22 sigma headroom
#define TILE  2048      // edges per block in k_bucket

typedef _Float16 f16x2 __attribute__((ext_vector_type(2)));

__device__ __forceinline__ float fdot2(unsigned int a, unsigned int b, float c) {
#if defined(__has_builtin) && __has_builtin(__builtin_amdgcn_fdot2)
    return __builtin_amdgcn_fdot2(__builtin_bit_cast(f16x2, a), __builtin_bit_cast(f16x2, b), c, false);
#else
    __half2 ah = __builtin_bit_cast(__half2, a), bh = __builtin_bit_cast(__half2, b);
    float2 af = __half22float2(ah), bf = __half22float2(bh);
    return c + af.x * bf.x + af.y * bf.y;
#endif
}

// ---------------- pass 1: bucket partition (proven) ----------------
__global__ __launch_bounds__(256) void k_bucket(const int* __restrict__ src,
                                                const int* __restrict__ dst,
                                                int* __restrict__ bcur,
                                                int* __restrict__ pairs, int E) {
    __shared__ int lcnt[NBUCK];
    __shared__ int gbase[NBUCK];
    const int t = threadIdx.x;
    for (int i = t; i < NBUCK; i += 256) lcnt[i] = 0;
    __syncthreads();
    const int base = blockIdx.x * TILE;
    int p[8], r[8], nb[8];
#pragma unroll
    for (int i = 0; i < 8; ++i) {
        int e = base + t + i * 256;
        if (e < E) {
            int s = src[e], d = dst[e];
            int b = d >> 10;
            nb[i] = b;
            p[i] = (s << 10) | (d & 1023);
            r[i] = atomicAdd(&lcnt[b], 1);
        }
    }
    __syncthreads();
    for (int i = t; i < NBUCK; i += 256)
        gbase[i] = lcnt[i] ? atomicAdd(&bcur[i], lcnt[i]) : 0;
    __syncthreads();
#pragma unroll
    for (int i = 0; i < 8; ++i) {
        int e = base + t + i * 256;
        if (e < E) {
            int pos = gbase[nb[i]] + r[i];
            if (pos < BCAP) pairs[nb[i] * BCAP + pos] = p[i];
        }
    }
}

// ---------------- tiny scan of 98 bucket sizes ----------------
__global__ __launch_bounds__(128) void k_bscan(const int* __restrict__ bcur,
                                               int* __restrict__ bOff, int nbk) {
    __shared__ int s[128];
    int t = threadIdx.x;
    int v = (t < nbk) ? bcur[t] : 0;
    s[t] = v;
    __syncthreads();
    for (int off = 1; off < 128; off <<= 1) {
        int u = (t >= off) ? s[t - off] : 0;
        __syncthreads();
        s[t] += u;
        __syncthreads();
    }
    if (t < nbk) bOff[t] = s[t] - v;
}

// ---------------- pass 2: per-bucket hist + scan + row_ptr/dinv + placement (proven) ----------------
__global__ __launch_bounds__(1024) void k_build(const int* __restrict__ pairs,
                                                const int* __restrict__ bcur,
                                                const int* __restrict__ bOff,
                                                int* __restrict__ row_ptr,
                                                float* __restrict__ dinv,
                                                int* __restrict__ col) {
    __shared__ int hist[1024];
    __shared__ int sm[1024];
    const int b = blockIdx.x;
    const int t = threadIdx.x;
    const int n = min(bcur[b], BCAP);
    const int base = bOff[b];
    const int* pp = pairs + b * BCAP;

    hist[t] = 0;
    __syncthreads();
    for (int i = t; i < n; i += 1024) atomicAdd(&hist[pp[i] & 1023], 1);
    __syncthreads();
    int c = hist[t];
    sm[t] = c;
    __syncthreads();
    for (int off = 1; off < 1024; off <<= 1) {
        int u = (t >= off) ? sm[t - off] : 0;
        __syncthreads();
        sm[t] += u;
        __syncthreads();
    }
    int rp = base + sm[t] - c;
    int gnode = (b << 10) + t;
    if (gnode < N_NODES_C) {
        row_ptr[gnode] = rp;
        dinv[gnode] = rsqrtf((float)(c + 1));
        if (gnode == N_NODES_C - 1) row_ptr[N_NODES_C] = rp + c;
    }
    __syncthreads();
    sm[t] = rp;
    __syncthreads();
    for (int i = t; i < n; i += 1024) {
        int p = pp[i];
        int idx = atomicAdd(&sm[p & 1023], 1);
        col[idx] = p >> 10;
    }
}

// ---------------- layer-1 transform: hs = (x @ W1) * dinv (proven) ----------------
__global__ __launch_bounds__(256) void k_mm0(const float* __restrict__ x,
                                             const float* __restrict__ W,
                                             const float* __restrict__ dinv,
                                             __half* __restrict__ hs, int n) {
    __shared__ float4 W4[IN_F_C * 16];
    const int t = threadIdx.x;
    for (int i = t; i < IN_F_C * 16; i += 256) {
        int k = i >> 4, f4 = i & 15;
        W4[i] = ((const float4*)(W + k * HID_C))[f4];
    }
    __syncthreads();
    int idx = blockIdx.x * 256 + t;
    if (idx >= n * 16) return;
    int nn = idx >> 4, f4 = idx & 15;
    const float* row = x + nn * IN_F_C;
    float4 acc = make_float4(0.f, 0.f, 0.f, 0.f);
#pragma unroll
    for (int k = 0; k < IN_F_C; ++k) {
        float xv = row[k];
        float4 w = W4[k * 16 + f4];
        acc.x += xv * w.x; acc.y += xv * w.y; acc.z += xv * w.z; acc.w += xv * w.w;
    }
    float di = dinv[nn];
    ((__half2*)hs)[(nn << 5) + 2 * f4]     = __floats2half2_rn(acc.x * di, acc.y * di);
    ((__half2*)hs)[(nn << 5) + 2 * f4 + 1] = __floats2half2_rn(acc.z * di, acc.w * di);
}

// ---------------- weight pre-pack: W[64][64] fp32 -> Wh[k8*64+f] = 8 halves of W[8k8..][f] ----------------
__global__ __launch_bounds__(256) void k_wcvt(const float* __restrict__ W, uint4* __restrict__ wh) {
    int i = blockIdx.x * 256 + threadIdx.x;      // 512 entries
    if (i >= 8 * HID_C) return;
    int k8 = i >> 3 >> 3, f = i & 63;
    k8 = i >> 6;
    __half2 h[4];
#pragma unroll
    for (int j = 0; j < 4; ++j)
        h[j] = __floats2half2_rn(W[(8 * k8 + 2 * j) * HID_C + f],
                                 W[(8 * k8 + 2 * j + 1) * HID_C + f]);
    wh[i] = *(uint4*)h;
}

// ---------------- fused: g-group gather (R8-proven) + epilogue + fdot2 transform (R12-proven) ----------------
__global__ __launch_bounds__(256) void k_gft(const int* __restrict__ row_ptr,
                                             const int* __restrict__ col,
                                             const __half* __restrict__ hsrc,
                                             const float* __restrict__ dinv,
                                             const float* __restrict__ bias,
                                             const uint4* __restrict__ wh,     // pre-packed fp16 W
                                             __half* __restrict__ hnext, int n) {
    __shared__ uint4 WhL[8 * HID_C];             // 8 KB
    __shared__ __half2 rowh[4][32];
    const int t = threadIdx.x;
#pragma unroll
    for (int i = 0; i < 2; ++i) WhL[t + i * 256] = wh[t + i * 256];
    __syncthreads();

    const int lane = t & 63;
    const int wid  = t >> 6;
    const int g    = lane >> 4;                  // edge group 0..3
    const int fl   = lane & 15;                  // feature-quad
    const int d = (blockIdx.x << 2) + wid;
    if (d >= n) return;
    const int beg = row_ptr[d];
    const int end = row_ptr[d + 1];
    const float2* hsv = (const float2*)hsrc;     // 8B = 4 halves per lane

    float4 acc = make_float4(0.f, 0.f, 0.f, 0.f);
    if (g == 0) {                                // self loop
        float2 raw = hsv[(d << 4) + fl];
        float2 a0 = __half22float2(*(__half2*)&raw.x);
        float2 a1 = __half22float2(*(__half2*)&raw.y);
        acc = make_float4(a0.x, a0.y, a1.x, a1.y);
    }
    int e = beg;
    for (; e + 15 < end; e += 16) {              // 16 edges/iter, 4 loads in flight/lane
        int s0 = col[e + g];
        int s1 = col[e + 4 + g];
        int s2 = col[e + 8 + g];
        int s3 = col[e + 12 + g];
        float2 r0 = hsv[(s0 << 4) + fl];
        float2 r1 = hsv[(s1 << 4) + fl];
        float2 r2 = hsv[(s2 << 4) + fl];
        float2 r3 = hsv[(s3 << 4) + fl];
        float2 a0 = __half22float2(*(__half2*)&r0.x), a1 = __half22float2(*(__half2*)&r0.y);
        float2 b0 = __half22float2(*(__half2*)&r1.x), b1 = __half22float2(*(__half2*)&r1.y);
        float2 c0 = __half22float2(*(__half2*)&r2.x), c1 = __half22float2(*(__half2*)&r2.y);
        float2 d0 = __half22float2(*(__half2*)&r3.x), d1 = __half22float2(*(__half2*)&r3.y);
        acc.x += (a0.x + b0.x) + (c0.x + d0.x);
        acc.y += (a0.y + b0.y) + (c0.y + d0.y);
        acc.z += (a1.x + b1.x) + (c1.x + d1.x);
        acc.w += (a1.y + b1.y) + (c1.y + d1.y);
    }
    for (; e < end; e += 4) {
        int i = e + g;
        if (i < end) {
            float2 r = hsv[(col[i] << 4) + fl];
            float2 a0 = __half22float2(*(__half2*)&r.x);
            float2 a1 = __half22float2(*(__half2*)&r.y);
            acc.x += a0.x; acc.y += a0.y; acc.z += a1.x; acc.w += a1.y;
        }
    }
    acc.x += __shfl_xor(acc.x, 16, 64); acc.y += __shfl_xor(acc.y, 16, 64);
    acc.z += __shfl_xor(acc.z, 16, 64); acc.w += __shfl_xor(acc.w, 16, 64);
    acc.x += __shfl_xor(acc.x, 32, 64); acc.y += __shfl_xor(acc.y, 32, 64);
    acc.z += __shfl_xor(acc.z, 32, 64); acc.w += __shfl_xor(acc.w, 32, 64);

    const float di = dinv[d];
    if (g == 0) {                                // epilogue -> fp16 act row in LDS
        float4 bb = ((const float4*)bias)[fl];
        float4 v;
        v.x = acc.x * di + bb.x; v.y = acc.y * di + bb.y;
        v.z = acc.z * di + bb.z; v.w = acc.w * di + bb.w;
        v.x = v.x > 0.f ? v.x : NEG_SLOPE_C * v.x;
        v.y = v.y > 0.f ? v.y : NEG_SLOPE_C * v.y;
        v.z = v.z > 0.f ? v.z : NEG_SLOPE_C * v.z;
        v.w = v.w > 0.f ? v.w : NEG_SLOPE_C * v.w;
        rowh[wid][2 * fl]     = __floats2half2_rn(v.x, v.y);
        rowh[wid][2 * fl + 1] = __floats2half2_rn(v.z, v.w);
    }
    // wave-synchronous LDS read-back; fdot2 transform (fp32 accumulate)
    {
        float s = 0.f;
        const uint4* rq = (const uint4*)rowh[wid];
#pragma unroll
        for (int k8 = 0; k8 < 8; ++k8) {
            uint4 wv = WhL[(k8 << 6) + lane];
            uint4 rv = rq[k8];                   // broadcast
            s = fdot2(rv.x, wv.x, s);
            s = fdot2(rv.y, wv.y, s);
            s = fdot2(rv.z, wv.z, s);
            s = fdot2(rv.w, wv.w, s);
        }
        hnext[(d << 6) + lane] = __float2half(s * di);
    }
}

// ---------------- fused: g-group gather + epilogue + final FC (R8 exact, 120.5us proven) ----------------
__global__ __launch_bounds__(256) void k_gfc(const int* __restrict__ row_ptr,
                                             const int* __restrict__ col,
                                             const __half* __restrict__ hsrc,
                                             const float* __restrict__ dinv,
                                             const float* __restrict__ bias,
                                             const float* __restrict__ Wn,   // [64][10]
                                             const float* __restrict__ bn,
                                             float* __restrict__ out, int n) {
    __shared__ float4 Ws4[16 * N_CLS_C];
    __shared__ float rowbuf[4][64];
    const int t = threadIdx.x;
    for (int i = t; i < 16 * N_CLS_C; i += 256) {
        int k4 = i / N_CLS_C, f = i - k4 * N_CLS_C;
        Ws4[i] = make_float4(Wn[(4 * k4 + 0) * N_CLS_C + f], Wn[(4 * k4 + 1) * N_CLS_C + f],
                             Wn[(4 * k4 + 2) * N_CLS_C + f], Wn[(4 * k4 + 3) * N_CLS_C + f]);
    }
    __syncthreads();

    const int lane = t & 63;
    const int wid  = t >> 6;
    const int g    = lane >> 4;
    const int fl   = lane & 15;
    const int d = (blockIdx.x << 2) + wid;
    if (d >= n) return;
    const int beg = row_ptr[d];
    const int end = row_ptr[d + 1];
    const float2* hsv = (const float2*)hsrc;

    float4 acc = make_float4(0.f, 0.f, 0.f, 0.f);
    if (g == 0) {
        float2 raw = hsv[(d << 4) + fl];
        float2 a0 = __half22float2(*(__half2*)&raw.x);
        float2 a1 = __half22float2(*(__half2*)&raw.y);
        acc = make_float4(a0.x, a0.y, a1.x, a1.y);
    }
    int e = beg;
    for (; e + 15 < end; e += 16) {
        int s0 = col[e + g];
        int s1 = col[e + 4 + g];
        int s2 = col[e + 8 + g];
        int s3 = col[e + 12 + g];
        float2 r0 = hsv[(s0 << 4) + fl];
        float2 r1 = hsv[(s1 << 4) + fl];
        float2 r2 = hsv[(s2 << 4) + fl];
        float2 r3 = hsv[(s3 << 4) + fl];
        float2 a0 = __half22float2(*(__half2*)&r0.x), a1 = __half22float2(*(__half2*)&r0.y);
        float2 b0 = __half22float2(*(__half2*)&r1.x), b1 = __half22float2(*(__half2*)&r1.y);
        float2 c0 = __half22float2(*(__half2*)&r2.x), c1 = __half22float2(*(__half2*)&r2.y);
        float2 d0 = __half22float2(*(__half2*)&r3.x), d1 = __half22float2(*(__half2*)&r3.y);
        acc.x += (a0.x + b0.x) + (c0.x + d0.x);
        acc.y += (a0.y + b0.y) + (c0.y + d0.y);
        acc.z += (a1.x + b1.x) + (c1.x + d1.x);
        acc.w += (a1.y + b1.y) + (c1.y + d1.y);
    }
    for (; e < end; e += 4) {
        int i = e + g;
        if (i < end) {
            float2 r = hsv[(col[i] << 4) + fl];
            float2 a0 = __half22float2(*(__half2*)&r.x);
            float2 a1 = __half22float2(*(__half2*)&r.y);
            acc.x += a0.x; acc.y += a0.y; acc.z += a1.x; acc.w += a1.y;
        }
    }
    acc.x += __shfl_xor(acc.x, 16, 64); acc.y += __shfl_xor(acc.y, 16, 64);
    acc.z += __shfl_xor(acc.z, 16, 64); acc.w += __shfl_xor(acc.w, 16, 64);
    acc.x += __shfl_xor(acc.x, 32, 64); acc.y += __shfl_xor(acc.y, 32, 64);
    acc.z += __shfl_xor(acc.z, 32, 64); acc.w += __shfl_xor(acc.w, 32, 64);

    const float di = dinv[d];
    if (g == 0) {
        float4 bb = ((const float4*)bias)[fl];
        float4 v;
        v.x = acc.x * di + bb.x; v.y = acc.y * di + bb.y;
        v.z = acc.z * di + bb.z; v.w = acc.w * di + bb.w;
        v.x = v.x > 0.f ? v.x : NEG_SLOPE_C * v.x;
        v.y = v.y > 0.f ? v.y : NEG_SLOPE_C * v.y;
        v.z = v.z > 0.f ? v.z : NEG_SLOPE_C * v.z;
        v.w = v.w > 0.f ? v.w : NEG_SLOPE_C * v.w;
        ((float4*)rowbuf[wid])[fl] = v;
    }
    if (lane < N_CLS_C) {
        float s = bn[lane];
        const float4* rb = (const float4*)rowbuf[wid];
#pragma unroll
        for (int k4 = 0; k4 < 16; ++k4) {
            float4 r4 = rb[k4];
            float4 w4 = Ws4[k4 * N_CLS_C + lane];
            s += r4.x * w4.x + r4.y * w4.y + r4.z * w4.z + r4.w * w4.w;
        }
        out[d * N_CLS_C + lane] = s;
    }
}

extern "C" void kernel_launch(void* const* d_in, const int* in_sizes, int n_in,
                              void* d_out, int out_size, void* d_ws, size_t ws_size,
                              hipStream_t stream) {
    const float* x   = (const float*)d_in[0];
    const int*   ei  = (const int*)d_in[1];
    const float* W1  = (const float*)d_in[2];
    const float* b1  = (const float*)d_in[3];
    const float* W2  = (const float*)d_in[4];
    const float* b2  = (const float*)d_in[5];
    const float* W3  = (const float*)d_in[6];
    const float* b3  = (const float*)d_in[7];
    const float* Wfc = (const float*)d_in[8];
    const float* bfc = (const float*)d_in[9];
    float* out = (float*)d_out;

    const int N = N_NODES_C;
    const int E = N_EDGES_C;
    const int* src = ei;
    const int* dst = ei + E;

    // workspace carve-up (16B aligned)
    float*  dinv    = (float*)d_ws;                   // N
    int*    bcur    = (int*)(dinv + N);               // 128 (zeroed)
    int*    bOff    = bcur + 128;                     // 128
    int*    row_ptr = bOff + 128;                     // N+4
    uint4*  wh2     = (uint4*)(row_ptr + N + 4);      // 512
    uint4*  wh3     = wh2 + 512;                      // 512
    int*    col     = (int*)(wh3 + 512);              // E
    int*    pairs   = col + E;                        // NBUCK*BCAP ints
    __half* hsA     = (__half*)pairs;                 // N*64 halves (aliases pairs; dead after k_build)
    __half* hsB     = (__half*)(pairs + (size_t)NBUCK * BCAP);

    int gN4 = (N + 3) / 4;                            // 25000
    int gM0 = (N * 16 + 255) / 256;                   // 6250
    int gBK = (E + TILE - 1) / TILE;                  // 1563

    // ---- CSR build (+ dinv) ----
    hipMemsetAsync(bcur, 0, 128 * sizeof(int), stream);
    k_bucket<<<gBK, 256, 0, stream>>>(src, dst, bcur, pairs, E);
    k_bscan<<<1, 128, 0, stream>>>(bcur, bOff, NBUCK);
    k_build<<<NBUCK, 1024, 0, stream>>>(pairs, bcur, bOff, row_ptr, dinv, col);

    // ---- weight pre-pack (fp16, 8-per-k layout) ----
    k_wcvt<<<2, 256, 0, stream>>>(W2, wh2);
    k_wcvt<<<2, 256, 0, stream>>>(W3, wh3);

    // ---- layer 1 transform ----
    k_mm0<<<gM0, 256, 0, stream>>>(x, W1, dinv, hsA, N);

    // ---- fused g-group gather + transform chain ----
    k_gft<<<gN4, 256, 0, stream>>>(row_ptr, col, hsA, dinv, b1, wh2, hsB, N);
    k_gft<<<gN4, 256, 0, stream>>>(row_ptr, col, hsB, dinv, b2, wh3, hsA, N);
    k_gfc<<<gN4, 256, 0, stream>>>(row_ptr, col, hsA, dinv, b3, Wfc, bfc, out, N);
}

// Round 15
// 395.001 us; speedup vs baseline: 2.0467x; 1.0499x over previous
//
#include <hip/hip_runtime.h>
#include <hip/hip_fp16.h>

#define N_NODES_C 100000
#define N_EDGES_C 3200000
#define IN_F_C 10
#define HID_C 64
#define N_CLS_C 10
#define NEG_SLOPE_C 0.01f

#define NBUCK 98        // ceil(100000/1024); bucket = dst >> 10
#define BCAP  36864     // mean 32768, sigma ~180 -> +22 sigma headroom
#define TILE  2048      // edges per block in k_bucket

typedef _Float16 f16x2 __attribute__((ext_vector_type(2)));

__device__ __forceinline__ float fdot2(unsigned int a, unsigned int b, float c) {
#if defined(__has_builtin) && __has_builtin(__builtin_amdgcn_fdot2)
    return __builtin_amdgcn_fdot2(__builtin_bit_cast(f16x2, a), __builtin_bit_cast(f16x2, b), c, false);
#else
    __half2 ah = __builtin_bit_cast(__half2, a), bh = __builtin_bit_cast(__half2, b);
    float2 af = __half22float2(ah), bf = __half22float2(bh);
    return c + af.x * bf.x + af.y * bf.y;
#endif
}

// ---------------- pass 1: bucket partition (proven) ----------------
__global__ __launch_bounds__(256) void k_bucket(const int* __restrict__ src,
                                                const int* __restrict__ dst,
                                                int* __restrict__ bcur,
                                                int* __restrict__ pairs, int E) {
    __shared__ int lcnt[NBUCK];
    __shared__ int gbase[NBUCK];
    const int t = threadIdx.x;
    for (int i = t; i < NBUCK; i += 256) lcnt[i] = 0;
    __syncthreads();
    const int base = blockIdx.x * TILE;
    int p[8], r[8], nb[8];
#pragma unroll
    for (int i = 0; i < 8; ++i) {
        int e = base + t + i * 256;
        if (e < E) {
            int s = src[e], d = dst[e];
            int b = d >> 10;
            nb[i] = b;
            p[i] = (s << 10) | (d & 1023);
            r[i] = atomicAdd(&lcnt[b], 1);
        }
    }
    __syncthreads();
    for (int i = t; i < NBUCK; i += 256)
        gbase[i] = lcnt[i] ? atomicAdd(&bcur[i], lcnt[i]) : 0;
    __syncthreads();
#pragma unroll
    for (int i = 0; i < 8; ++i) {
        int e = base + t + i * 256;
        if (e < E) {
            int pos = gbase[nb[i]] + r[i];
            if (pos < BCAP) pairs[nb[i] * BCAP + pos] = p[i];
        }
    }
}

// ---------------- pass 2: per-bucket hist + scan + row_ptr/dinv + placement; bucket-prefix fused ----------------
__global__ __launch_bounds__(1024) void k_build(const int* __restrict__ pairs,
                                                const int* __restrict__ bcur,
                                                int* __restrict__ row_ptr,
                                                float* __restrict__ dinv,
                                                int* __restrict__ col) {
    __shared__ int hist[1024];
    __shared__ int sm[1024];
    __shared__ int bs[128];
    const int b = blockIdx.x;
    const int t = threadIdx.x;
    const int n = min(bcur[b], BCAP);
    const int* pp = pairs + b * BCAP;

    // fused bucket-prefix (inclusive scan of bcur over 98 buckets)
    if (t < 128) bs[t] = (t < NBUCK) ? bcur[t] : 0;
    __syncthreads();
    for (int off = 1; off < 128; off <<= 1) {
        int u = 0;
        if (t < 128 && t >= off) u = bs[t - off];
        __syncthreads();
        if (t < 128) bs[t] += u;
        __syncthreads();
    }
    const int base = (b > 0) ? bs[b - 1] : 0;

    hist[t] = 0;
    __syncthreads();
    for (int i = t; i < n; i += 1024) atomicAdd(&hist[pp[i] & 1023], 1);
    __syncthreads();
    int c = hist[t];
    sm[t] = c;
    __syncthreads();
    for (int off = 1; off < 1024; off <<= 1) {
        int u = (t >= off) ? sm[t - off] : 0;
        __syncthreads();
        sm[t] += u;
        __syncthreads();
    }
    int rp = base + sm[t] - c;
    int gnode = (b << 10) + t;
    if (gnode < N_NODES_C) {
        row_ptr[gnode] = rp;
        dinv[gnode] = rsqrtf((float)(c + 1));
        if (gnode == N_NODES_C - 1) row_ptr[N_NODES_C] = rp + c;
    }
    __syncthreads();
    sm[t] = rp;
    __syncthreads();
    for (int i = t; i < n; i += 1024) {
        int p = pp[i];
        int idx = atomicAdd(&sm[p & 1023], 1);
        col[idx] = p >> 10;
    }
}

// ---------------- layer-1 transform: hs = (x @ W1) * dinv (proven) ----------------
__global__ __launch_bounds__(256) void k_mm0(const float* __restrict__ x,
                                             const float* __restrict__ W,
                                             const float* __restrict__ dinv,
                                             __half* __restrict__ hs, int n) {
    __shared__ float4 W4[IN_F_C * 16];
    const int t = threadIdx.x;
    for (int i = t; i < IN_F_C * 16; i += 256) {
        int k = i >> 4, f4 = i & 15;
        W4[i] = ((const float4*)(W + k * HID_C))[f4];
    }
    __syncthreads();
    int idx = blockIdx.x * 256 + t;
    if (idx >= n * 16) return;
    int nn = idx >> 4, f4 = idx & 15;
    const float* row = x + nn * IN_F_C;
    float4 acc = make_float4(0.f, 0.f, 0.f, 0.f);
#pragma unroll
    for (int k = 0; k < IN_F_C; ++k) {
        float xv = row[k];
        float4 w = W4[k * 16 + f4];
        acc.x += xv * w.x; acc.y += xv * w.y; acc.z += xv * w.z; acc.w += xv * w.w;
    }
    float di = dinv[nn];
    ((__half2*)hs)[(nn << 5) + 2 * f4]     = __floats2half2_rn(acc.x * di, acc.y * di);
    ((__half2*)hs)[(nn << 5) + 2 * f4 + 1] = __floats2half2_rn(acc.z * di, acc.w * di);
}

// ---------------- weight pre-pack: W[64][64] fp32 -> Wh[k8*64+f] = 8 halves ----------------
__global__ __launch_bounds__(256) void k_wcvt(const float* __restrict__ W, uint4* __restrict__ wh) {
    int i = blockIdx.x * 256 + threadIdx.x;      // 512 entries
    if (i >= 8 * HID_C) return;
    int k8 = i >> 6, f = i & 63;
    __half2 h[4];
#pragma unroll
    for (int j = 0; j < 4; ++j)
        h[j] = __floats2half2_rn(W[(8 * k8 + 2 * j) * HID_C + f],
                                 W[(8 * k8 + 2 * j + 1) * HID_C + f]);
    wh[i] = *(uint4*)h;
}

// ---------------- Wfc pre-pack: Ws4[k4*10+f] = {Wfc[4k4+j][f]} fp32 quads ----------------
__global__ __launch_bounds__(256) void k_wcvtf(const float* __restrict__ W, float4* __restrict__ wq) {
    int i = threadIdx.x;                         // 160 entries
    if (i >= 16 * N_CLS_C) return;
    int k4 = i / N_CLS_C, f = i - k4 * N_CLS_C;
    wq[i] = make_float4(W[(4 * k4 + 0) * N_CLS_C + f], W[(4 * k4 + 1) * N_CLS_C + f],
                        W[(4 * k4 + 2) * N_CLS_C + f], W[(4 * k4 + 3) * N_CLS_C + f]);
}

// ---------------- fused: g-group gather + epilogue + fdot2 transform (8 waves/block) ----------------
__global__ __launch_bounds__(512) void k_gft(const int* __restrict__ row_ptr,
                                             const int* __restrict__ col,
                                             const __half* __restrict__ hsrc,
                                             const float* __restrict__ dinv,
                                             const float* __restrict__ bias,
                                             const uint4* __restrict__ wh,     // pre-packed fp16 W
                                             __half* __restrict__ hnext, int n) {
    __shared__ uint4 WhL[8 * HID_C];             // 8 KB
    __shared__ __half2 rowh[8][32];
    const int t = threadIdx.x;
    WhL[t] = wh[t];                              // 512 threads, 512 entries
    __syncthreads();

    const int lane = t & 63;
    const int wid  = t >> 6;                     // 0..7
    const int g    = lane >> 4;                  // edge group 0..3
    const int fl   = lane & 15;                  // feature-quad
    const int d = (blockIdx.x << 3) + wid;
    if (d >= n) return;
    const int beg = row_ptr[d];
    const int end = row_ptr[d + 1];
    const float2* hsv = (const float2*)hsrc;     // 8B = 4 halves per lane

    float4 acc = make_float4(0.f, 0.f, 0.f, 0.f);
    if (g == 0) {                                // self loop
        float2 raw = hsv[(d << 4) + fl];
        float2 a0 = __half22float2(*(__half2*)&raw.x);
        float2 a1 = __half22float2(*(__half2*)&raw.y);
        acc = make_float4(a0.x, a0.y, a1.x, a1.y);
    }
    int e = beg;
    for (; e + 15 < end; e += 16) {              // 16 edges/iter, 4 loads in flight/lane
        int s0 = col[e + g];
        int s1 = col[e + 4 + g];
        int s2 = col[e + 8 + g];
        int s3 = col[e + 12 + g];
        float2 r0 = hsv[(s0 << 4) + fl];
        float2 r1 = hsv[(s1 << 4) + fl];
        float2 r2 = hsv[(s2 << 4) + fl];
        float2 r3 = hsv[(s3 << 4) + fl];
        float2 a0 = __half22float2(*(__half2*)&r0.x), a1 = __half22float2(*(__half2*)&r0.y);
        float2 b0 = __half22float2(*(__half2*)&r1.x), b1 = __half22float2(*(__half2*)&r1.y);
        float2 c0 = __half22float2(*(__half2*)&r2.x), c1 = __half22float2(*(__half2*)&r2.y);
        float2 d0 = __half22float2(*(__half2*)&r3.x), d1 = __half22float2(*(__half2*)&r3.y);
        acc.x += (a0.x + b0.x) + (c0.x + d0.x);
        acc.y += (a0.y + b0.y) + (c0.y + d0.y);
        acc.z += (a1.x + b1.x) + (c1.x + d1.x);
        acc.w += (a1.y + b1.y) + (c1.y + d1.y);
    }
    for (; e < end; e += 4) {
        int i = e + g;
        if (i < end) {
            float2 r = hsv[(col[i] << 4) + fl];
            float2 a0 = __half22float2(*(__half2*)&r.x);
            float2 a1 = __half22float2(*(__half2*)&r.y);
            acc.x += a0.x; acc.y += a0.y; acc.z += a1.x; acc.w += a1.y;
        }
    }
    acc.x += __shfl_xor(acc.x, 16, 64); acc.y += __shfl_xor(acc.y, 16, 64);
    acc.z += __shfl_xor(acc.z, 16, 64); acc.w += __shfl_xor(acc.w, 16, 64);
    acc.x += __shfl_xor(acc.x, 32, 64); acc.y += __shfl_xor(acc.y, 32, 64);
    acc.z += __shfl_xor(acc.z, 32, 64); acc.w += __shfl_xor(acc.w, 32, 64);

    const float di = dinv[d];
    if (g == 0) {                                // epilogue -> fp16 act row in LDS
        float4 bb = ((const float4*)bias)[fl];
        float4 v;
        v.x = acc.x * di + bb.x; v.y = acc.y * di + bb.y;
        v.z = acc.z * di + bb.z; v.w = acc.w * di + bb.w;
        v.x = v.x > 0.f ? v.x : NEG_SLOPE_C * v.x;
        v.y = v.y > 0.f ? v.y : NEG_SLOPE_C * v.y;
        v.z = v.z > 0.f ? v.z : NEG_SLOPE_C * v.z;
        v.w = v.w > 0.f ? v.w : NEG_SLOPE_C * v.w;
        rowh[wid][2 * fl]     = __floats2half2_rn(v.x, v.y);
        rowh[wid][2 * fl + 1] = __floats2half2_rn(v.z, v.w);
    }
    // wave-synchronous LDS read-back; fdot2 transform (fp32 accumulate)
    {
        float s = 0.f;
        const uint4* rq = (const uint4*)rowh[wid];
#pragma unroll
        for (int k8 = 0; k8 < 8; ++k8) {
            uint4 wv = WhL[(k8 << 6) + lane];
            uint4 rv = rq[k8];                   // broadcast
            s = fdot2(rv.x, wv.x, s);
            s = fdot2(rv.y, wv.y, s);
            s = fdot2(rv.z, wv.z, s);
            s = fdot2(rv.w, wv.w, s);
        }
        hnext[(d << 6) + lane] = __float2half(s * di);
    }
}

// ---------------- fused: g-group gather + epilogue + final FC (prepacked fp32 quads, 8 waves/block) ----------------
__global__ __launch_bounds__(512) void k_gfc(const int* __restrict__ row_ptr,
                                             const int* __restrict__ col,
                                             const __half* __restrict__ hsrc,
                                             const float* __restrict__ dinv,
                                             const float* __restrict__ bias,
                                             const float4* __restrict__ wq,   // pre-packed Wfc quads
                                             const float* __restrict__ bn,
                                             float* __restrict__ out, int n) {
    __shared__ float4 Ws4[16 * N_CLS_C];
    __shared__ float rowbuf[8][64];
    const int t = threadIdx.x;
    if (t < 16 * N_CLS_C) Ws4[t] = wq[t];        // one coalesced float4 load
    __syncthreads();

    const int lane = t & 63;
    const int wid  = t >> 6;
    const int g    = lane >> 4;
    const int fl   = lane & 15;
    const int d = (blockIdx.x << 3) + wid;
    if (d >= n) return;
    const int beg = row_ptr[d];
    const int end = row_ptr[d + 1];
    const float2* hsv = (const float2*)hsrc;

    float4 acc = make_float4(0.f, 0.f, 0.f, 0.f);
    if (g == 0) {
        float2 raw = hsv[(d << 4) + fl];
        float2 a0 = __half22float2(*(__half2*)&raw.x);
        float2 a1 = __half22float2(*(__half2*)&raw.y);
        acc = make_float4(a0.x, a0.y, a1.x, a1.y);
    }
    int e = beg;
    for (; e + 15 < end; e += 16) {
        int s0 = col[e + g];
        int s1 = col[e + 4 + g];
        int s2 = col[e + 8 + g];
        int s3 = col[e + 12 + g];
        float2 r0 = hsv[(s0 << 4) + fl];
        float2 r1 = hsv[(s1 << 4) + fl];
        float2 r2 = hsv[(s2 << 4) + fl];
        float2 r3 = hsv[(s3 << 4) + fl];
        float2 a0 = __half22float2(*(__half2*)&r0.x), a1 = __half22float2(*(__half2*)&r0.y);
        float2 b0 = __half22float2(*(__half2*)&r1.x), b1 = __half22float2(*(__half2*)&r1.y);
        float2 c0 = __half22float2(*(__half2*)&r2.x), c1 = __half22float2(*(__half2*)&r2.y);
        float2 d0 = __half22float2(*(__half2*)&r3.x), d1 = __half22float2(*(__half2*)&r3.y);
        acc.x += (a0.x + b0.x) + (c0.x + d0.x);
        acc.y += (a0.y + b0.y) + (c0.y + d0.y);
        acc.z += (a1.x + b1.x) + (c1.x + d1.x);
        acc.w += (a1.y + b1.y) + (c1.y + d1.y);
    }
    for (; e < end; e += 4) {
        int i = e + g;
        if (i < end) {
            float2 r = hsv[(col[i] << 4) + fl];
            float2 a0 = __half22float2(*(__half2*)&r.x);
            float2 a1 = __half22float2(*(__half2*)&r.y);
            acc.x += a0.x; acc.y += a0.y; acc.z += a1.x; acc.w += a1.y;
        }
    }
    acc.x += __shfl_xor(acc.x, 16, 64); acc.y += __shfl_xor(acc.y, 16, 64);
    acc.z += __shfl_xor(acc.z, 16, 64); acc.w += __shfl_xor(acc.w, 16, 64);
    acc.x += __shfl_xor(acc.x, 32, 64); acc.y += __shfl_xor(acc.y, 32, 64);
    acc.z += __shfl_xor(acc.z, 32, 64); acc.w += __shfl_xor(acc.w, 32, 64);

    const float di = dinv[d];
    if (g == 0) {
        float4 bb = ((const float4*)bias)[fl];
        float4 v;
        v.x = acc.x * di + bb.x; v.y = acc.y * di + bb.y;
        v.z = acc.z * di + bb.z; v.w = acc.w * di + bb.w;
        v.x = v.x > 0.f ? v.x : NEG_SLOPE_C * v.x;
        v.y = v.y > 0.f ? v.y : NEG_SLOPE_C * v.y;
        v.z = v.z > 0.f ? v.z : NEG_SLOPE_C * v.z;
        v.w = v.w > 0.f ? v.w : NEG_SLOPE_C * v.w;
        ((float4*)rowbuf[wid])[fl] = v;
    }
    if (lane < N_CLS_C) {
        float s = bn[lane];
        const float4* rb = (const float4*)rowbuf[wid];
#pragma unroll
        for (int k4 = 0; k4 < 16; ++k4) {
            float4 r4 = rb[k4];
            float4 w4 = Ws4[k4 * N_CLS_C + lane];
            s += r4.x * w4.x + r4.y * w4.y + r4.z * w4.z + r4.w * w4.w;
        }
        out[d * N_CLS_C + lane] = s;
    }
}

extern "C" void kernel_launch(void* const* d_in, const int* in_sizes, int n_in,
                              void* d_out, int out_size, void* d_ws, size_t ws_size,
                              hipStream_t stream) {
    const float* x   = (const float*)d_in[0];
    const int*   ei  = (const int*)d_in[1];
    const float* W1  = (const float*)d_in[2];
    const float* b1  = (const float*)d_in[3];
    const float* W2  = (const float*)d_in[4];
    const float* b2  = (const float*)d_in[5];
    const float* W3  = (const float*)d_in[6];
    const float* b3  = (const float*)d_in[7];
    const float* Wfc = (const float*)d_in[8];
    const float* bfc = (const float*)d_in[9];
    float* out = (float*)d_out;

    const int N = N_NODES_C;
    const int E = N_EDGES_C;
    const int* src = ei;
    const int* dst = ei + E;

    // workspace carve-up (16B aligned)
    float*  dinv    = (float*)d_ws;                   // N
    int*    bcur    = (int*)(dinv + N);               // 128 (zeroed)
    int*    row_ptr = bcur + 128;                     // N+4
    uint4*  wh2     = (uint4*)(row_ptr + N + 4);      // 512
    uint4*  wh3     = wh2 + 512;                      // 512
    float4* wfcq    = (float4*)(wh3 + 512);           // 160 (pad 160)
    int*    col     = (int*)(wfcq + 160);             // E
    int*    pairs   = col + E;                        // NBUCK*BCAP ints
    __half* hsA     = (__half*)pairs;                 // N*64 halves (aliases pairs; dead after k_build)
    __half* hsB     = (__half*)(pairs + (size_t)NBUCK * BCAP);

    int gN8 = (N + 7) / 8;                            // 12500
    int gM0 = (N * 16 + 255) / 256;                   // 6250
    int gBK = (E + TILE - 1) / TILE;                  // 1563

    // ---- CSR build (+ dinv) ----
    hipMemsetAsync(bcur, 0, 128 * sizeof(int), stream);
    k_bucket<<<gBK, 256, 0, stream>>>(src, dst, bcur, pairs, E);
    k_build<<<NBUCK, 1024, 0, stream>>>(pairs, bcur, row_ptr, dinv, col);

    // ---- weight pre-pack ----
    k_wcvt<<<2, 256, 0, stream>>>(W2, wh2);
    k_wcvt<<<2, 256, 0, stream>>>(W3, wh3);
    k_wcvtf<<<1, 256, 0, stream>>>(Wfc, wfcq);

    // ---- layer 1 transform ----
    k_mm0<<<gM0, 256, 0, stream>>>(x, W1, dinv, hsA, N);

    // ---- fused g-group gather + transform chain ----
    k_gft<<<gN8, 512, 0, stream>>>(row_ptr, col, hsA, dinv, b1, wh2, hsB, N);
    k_gft<<<gN8, 512, 0, stream>>>(row_ptr, col, hsB, dinv, b2, wh3, hsA, N);
    k_gfc<<<gN8, 512, 0, stream>>>(row_ptr, col, hsA, dinv, b3, wfcq, bfc, out, N);
}